// Round 10
// baseline (162.569 us; speedup 1.0000x reference)
//
#include <hip/hip_runtime.h>
#include <hip/hip_bf16.h>
#include <stdint.h>

typedef unsigned short u16;
typedef unsigned int u32;
typedef _Float16 f16x8 __attribute__((ext_vector_type(8)));
typedef float f32x4 __attribute__((ext_vector_type(4)));

#define QKSCALE (0.044194173824159216f * 1.4426950408889634f)  // 1/sqrt(512) * log2e

__device__ __forceinline__ u16 f2h(float f) {
  return __builtin_bit_cast(u16, (_Float16)f);
}

__device__ __forceinline__ void gload_lds16(const void* g, void* l) {
  __builtin_amdgcn_global_load_lds(
      (const __attribute__((address_space(1))) u32*)g,
      (__attribute__((address_space(3))) u32*)l, 16, 0, 0);
}

// ---------------- concat + f32->f16 ----------------
__global__ void k_concat_f16(const float* __restrict__ x, const float* __restrict__ y,
                             u16* __restrict__ xyh) {
  int tid = blockIdx.x * blockDim.x + threadIdx.x;
  int e = tid * 4;
  int s = e >> 9;
  int d = e & 511;
  int b = s >> 11, r = s & 2047;
  const float* src = (r < 1024) ? (x + ((size_t)(b * 1024 + r) * 512 + d))
                                : (y + ((size_t)(b * 1024 + (r - 1024)) * 512 + d));
  float4 v = *(const float4*)src;
  ushort4 o;
  o.x = f2h(v.x); o.y = f2h(v.y); o.z = f2h(v.z); o.w = f2h(v.w);
  *(ushort4*)(xyh + e) = o;
}

// ---------------- W~ = Wq^T * Wk, e-split partials ----------------
// grid 256 = 64 (i,j)-tiles x 4 e-groups(128 e); wpart[eg][j][i] f32 (transposed: W~T)
__global__ __launch_bounds__(256) void k_wtilde_part(const float* __restrict__ Wq,
                                                     const float* __restrict__ Wk,
                                                     float* __restrict__ wpart) {
  int blk = blockIdx.x;
  int eg = blk >> 6, tile = blk & 63;
  int i0 = (tile >> 3) * 64, j0 = (tile & 7) * 64;
  int t = threadIdx.x;
  __shared__ float qs[64][64], ks[64][64];
  int ti = t >> 4, tj = t & 15;  // 16x16 threads, 4x4 outputs each
  float acc[4][4] = {};
  for (int ec = eg * 128; ec < eg * 128 + 128; ec += 64) {
    __syncthreads();
#pragma unroll
    for (int r = 0; r < 4; ++r) {
      int e = (t >> 4) + r * 16;
      int c = (t & 15) * 4;
      *(float4*)&qs[e][c] = *(const float4*)(Wq + (size_t)(ec + e) * 512 + i0 + c);
      *(float4*)&ks[e][c] = *(const float4*)(Wk + (size_t)(ec + e) * 512 + j0 + c);
    }
    __syncthreads();
#pragma unroll 8
    for (int e = 0; e < 64; ++e) {
      float4 qa = *(const float4*)&qs[e][ti * 4];
      float4 kb = *(const float4*)&ks[e][tj * 4];
      float qv[4] = {qa.x, qa.y, qa.z, qa.w}, kv[4] = {kb.x, kb.y, kb.z, kb.w};
#pragma unroll
      for (int a = 0; a < 4; ++a)
#pragma unroll
        for (int b = 0; b < 4; ++b) acc[a][b] += qv[a] * kv[b];
    }
  }
  float* base = wpart + (size_t)eg * 262144;
#pragma unroll
  for (int b = 0; b < 4; ++b) {
    float4 o = {acc[0][b], acc[1][b], acc[2][b], acc[3][b]};
    *(float4*)(base + (size_t)(j0 + tj * 4 + b) * 512 + i0 + ti * 4) = o;
  }
}

// ---------------- finalize W~T (sum 4 partials, fold QK scale -> f16) + Wv -> f16 ----------------
__global__ __launch_bounds__(256) void k_wfin(const float* __restrict__ wpart,
                                              const float* __restrict__ Wv,
                                              u16* __restrict__ WtT, u16* __restrict__ Wvh) {
  int blk = blockIdx.x, t = threadIdx.x;
  if (blk < 64) {
    int base = blk * 4096 + t * 16;
#pragma unroll
    for (int g = 0; g < 4; ++g) {
      float4 s = *(const float4*)(wpart + base + g * 4);
#pragma unroll
      for (int eg = 1; eg < 4; ++eg) {
        float4 p = *(const float4*)(wpart + (size_t)eg * 262144 + base + g * 4);
        s.x += p.x; s.y += p.y; s.z += p.z; s.w += p.w;
      }
      ushort4 o;
      o.x = f2h(s.x * QKSCALE); o.y = f2h(s.y * QKSCALE);
      o.z = f2h(s.z * QKSCALE); o.w = f2h(s.w * QKSCALE);
      *(ushort4*)(WtT + base + g * 4) = o;
    }
  } else {
    int base = (blk - 64) * 65536;
#pragma unroll 16
    for (int r = 0; r < 64; ++r) {
      int e = base + (r * 256 + t) * 4;
      float4 v = *(const float4*)(Wv + e);
      ushort4 o;
      o.x = f2h(v.x); o.y = f2h(v.y); o.z = f2h(v.z); o.w = f2h(v.w);
      *(ushort4*)(Wvh + e) = o;
    }
  }
}

// ---------------- 128x128 / BK=32 / 4-wave GEMM (m97 geometry): C = scale * A * B^T ----
// 4 waves 2x2, wave tile 64x64, M_rep=N_rep=4, 16 MFMA + 8 ds_read_b128 per K-tile.
// LDS = 2 x (A 8KB + B 8KB) = 32 KB -> 3-5 blocks/CU (TLP hides end-of-tile drains).
// 64B LDS rows, swizzle: storage(row, cb) = row*64 + (cb ^ (((row>>1)&3)<<4))
//   -> b128 fragment reads hit 8 distinct 16B bank-slots per 16-lane group (2-way, free).
// Staged via global_load_lds with pre-swizzled SOURCE (linear LDS dest), double-buffered;
// stage ALL of tile kt+1 at top of tile kt; one vmcnt(0)+syncthreads per tile.
// MODE 0: C=f16(acc*scale). MODE 1: C=f16(exp2(acc*scale)) + row sums ->
//   lextra[(z*2048+row)*ntiles+ty]. MODE 2: C=f32(acc*scale*lextra[z*2048+row]).
template <int MODE>
__global__ __launch_bounds__(256, 2) void k_gemm128(
    const u16* __restrict__ A, const u16* __restrict__ B, void* __restrict__ Cv,
    int lda, int ldb, int ldc,
    long long sA, long long sB, long long sC,
    int K, float scale, int batches, int mtiles, int ntiles,
    float* __restrict__ lextra) {
  __shared__ __align__(16) char lds[2 * 16384];

  int t = threadIdx.x, lane = t & 63, w = t >> 6;
  int wr = w >> 1, wc = w & 1;

  int bid = blockIdx.x;
  long long z = bid % batches;
  int t2 = bid / batches;
  int tx = t2 % mtiles, ty = t2 / mtiles;

  size_t rsA = (size_t)lda * 2, rsB = (size_t)ldb * 2;
  int srow = t >> 2;                                        // 0..63
  int scb = ((t & 3) * 16) ^ (((srow >> 1) & 3) << 4);      // pre-swizzled source col byte

  const char* Ab = (const char*)(A + z * sA + (size_t)tx * 128 * lda);
  const char* Bb = (const char*)(B + z * sB + (size_t)ty * 128 * ldb);

  const char* gsrc[4];
  gsrc[0] = Ab + (size_t)srow * rsA + scb;
  gsrc[1] = Ab + (size_t)(64 + srow) * rsA + scb;
  gsrc[2] = Bb + (size_t)srow * rsB + scb;
  gsrc[3] = Bb + (size_t)(64 + srow) * rsB + scb;

  auto stageAll = [&](int buf) {
#pragma unroll
    for (int r = 0; r < 4; ++r) {
      gload_lds16(gsrc[r], lds + buf * 16384 + r * 4096 + t * 16);
      gsrc[r] += 64;  // advance one K-tile (32 f16 = 64B)
    }
  };

  int arow0 = wr * 64 + (lane & 15);
  int brow0 = wc * 64 + (lane & 15);
  int sw_a = ((arow0 >> 1) & 3) << 4;  // m*16 doesn't change ((row>>1)&3)
  int sw_b = ((brow0 >> 1) & 3) << 4;
  int cb = (lane >> 4) << 4;
  int aoff = arow0 * 64 + (cb ^ sw_a);
  int boff = 8192 + brow0 * 64 + (cb ^ sw_b);

  f32x4 acc[4][4] = {};
  int NT = K >> 5;

  stageAll(0);
  asm volatile("s_waitcnt vmcnt(0)" ::: "memory");
  __syncthreads();

  for (int kt = 0; kt < NT; ++kt) {
    const char* base = lds + (kt & 1) * 16384;
    if (kt + 1 < NT) stageAll((kt & 1) ^ 1);
    __builtin_amdgcn_sched_barrier(0);

    f16x8 afr[4], bfr[4];
#pragma unroll
    for (int i = 0; i < 4; ++i) {
      afr[i] = *(const f16x8*)(base + aoff + i * 1024);
      bfr[i] = *(const f16x8*)(base + boff + i * 1024);
    }
    __builtin_amdgcn_s_setprio(1);
#pragma unroll
    for (int i = 0; i < 4; ++i)
#pragma unroll
      for (int j = 0; j < 4; ++j)
        acc[i][j] = __builtin_amdgcn_mfma_f32_16x16x32_f16(afr[i], bfr[j], acc[i][j], 0, 0, 0);
    __builtin_amdgcn_s_setprio(0);
    __builtin_amdgcn_sched_barrier(0);

    if (kt + 1 < NT) {
      asm volatile("s_waitcnt vmcnt(0)" ::: "memory");
      __syncthreads();
    }
  }

  // ---------------- epilogue ----------------
  float* lds_l = (float*)lds;  // [128][2] (MODE 1 only)
  if constexpr (MODE == 1) __syncthreads();

#pragma unroll
  for (int m = 0; m < 4; ++m) {
    int lrow = wr * 64 + m * 16 + ((lane >> 4) << 2);
    int grow = tx * 128 + lrow;
#pragma unroll
    for (int r = 0; r < 4; ++r) {
      float rs = 0.0f;
      float lv = 1.0f;
      if constexpr (MODE == 2) lv = lextra[z * 2048 + grow + r];
#pragma unroll
      for (int n = 0; n < 4; ++n) {
        int col = ty * 128 + wc * 64 + n * 16 + (lane & 15);
        float v = acc[m][n][r] * scale;
        size_t idx = (size_t)(z * sC) + (size_t)(grow + r) * ldc + col;
        if constexpr (MODE == 0) {
          ((_Float16*)Cv)[idx] = (_Float16)v;
        } else if constexpr (MODE == 1) {
          _Float16 h = (_Float16)exp2f(v);
          ((_Float16*)Cv)[idx] = h;
          rs += (float)h;  // sum rounded values so O/l is unbiased
        } else {
          ((float*)Cv)[idx] = v * lv;
        }
      }
      if constexpr (MODE == 1) {
        rs += __shfl_xor(rs, 1, 16);
        rs += __shfl_xor(rs, 2, 16);
        rs += __shfl_xor(rs, 4, 16);
        rs += __shfl_xor(rs, 8, 16);
        if ((lane & 15) == 0) lds_l[(lrow + r) * 2 + wc] = rs;
      }
    }
  }

  if constexpr (MODE == 1) {
    __syncthreads();
    if (t < 128) {
      float s = lds_l[t * 2] + lds_l[t * 2 + 1];
      lextra[(z * 2048 + tx * 128 + t) * ntiles + ty] = s;
    }
  }
}

// ---------------- invert row sums ----------------
__global__ __launch_bounds__(256) void k_inv_l(const float* __restrict__ lpart,
                                               float* __restrict__ linv,
                                               int mrows, int rowoff, int nparts) {
  int tid = blockIdx.x * blockDim.x + threadIdx.x;
  int z = tid / mrows, lr = tid - z * mrows;
  int row = z * 2048 + rowoff + lr;
  const float* p = lpart + (size_t)row * nparts;
  float s = 0.0f;
  for (int q = 0; q < nparts; ++q) s += p[q];
  linv[row] = 1.0f / s;
}

extern "C" void kernel_launch(void* const* d_in, const int* in_sizes, int n_in,
                              void* d_out, int out_size, void* d_ws, size_t ws_size,
                              hipStream_t stream) {
  const float* x = (const float*)d_in[0];
  const float* y = (const float*)d_in[1];
  const float* Wq = (const float*)d_in[2];
  const float* Wk = (const float*)d_in[3];
  const float* Wv = (const float*)d_in[4];
  float* out = (float*)d_out;

  char* p = (char*)d_ws;
  u16* xyh = (u16*)p; p += (size_t)16384 * 512 * 2;   // concat f16 (alive thru QK^T)
  u16* Qt  = (u16*)p; p += (size_t)16384 * 512 * 2;   // Q~ = xy*(W~*scale) f16
  u16* VTh = (u16*)p; p += (size_t)16384 * 512 * 2;   // V^T f16 [512][16384]
  float* lpart = (float*)p; p += (size_t)16384 * 16 * 4;  // 1 MB partial row sums
  float* linv = (float*)p; p += (size_t)16384 * 4;
  u16* WtT = (u16*)p; p += (size_t)512 * 512 * 2;     // W~^T f16 (scale folded)
  u16* Wvh = (u16*)p; p += (size_t)512 * 512 * 2;
  size_t base = (size_t)(p - (char*)d_ws);
  float* wpart = (float*)p;    // 4 MB, dead before S written
  _Float16* Sb = (_Float16*)p; // S/P region

  int nc = (ws_size >= base + (size_t)16384 * 2048 * 2) ? 1 : 2;
  int mrows = 2048 / nc;
  int mt = mrows / 128;

  // converts + W~ precompute
  k_concat_f16<<<8192, 256, 0, stream>>>(x, y, xyh);
  k_wtilde_part<<<256, 256, 0, stream>>>(Wq, Wk, wpart);
  k_wfin<<<68, 256, 0, stream>>>(wpart, Wv, WtT, Wvh);

  // Q~ projection: [16384][512] = xy @ WtT^T  (f16 out)   grid 128x4
  k_gemm128<0><<<512, 256, 0, stream>>>(
      xyh, WtT, Qt, 512, 512, 512, 0, 0, 0, 512, 1.0f, 1, 128, 4, nullptr);
  // VT projection: [512][16384] = Wv @ xy^T  (f16 out)    grid 4x128
  k_gemm128<0><<<512, 256, 0, stream>>>(
      Wvh, xyh, VTh, 512, 512, 16384, 0, 0, 0, 512, 1.0f, 1, 4, 128, nullptr);

  for (int c = 0; c < nc; ++c) {
    const u16* Qc = Qt + (size_t)c * mrows * 512;
    // P = exp2(Q~ xy^T) (f16 out, scale pre-folded) + row partial sums -> lpart
    k_gemm128<1><<<8 * mt * 16, 256, 0, stream>>>(
        Qc, xyh, Sb, 512, 512, 2048,
        (long long)2048 * 512, (long long)2048 * 512, (long long)mrows * 2048,
        512, 1.0f, 8, mt, 16, lpart + (size_t)c * mrows * 16);
    // linv = 1 / rowsum
    k_inv_l<<<(8 * mrows) / 256, 256, 0, stream>>>(lpart, linv, mrows, c * mrows, 16);
    // O = (P @ VT^T) * linv (f16 in, f32 out)
    k_gemm128<2><<<8 * mt * 4, 256, 0, stream>>>(
        (const u16*)Sb, VTh, out + (size_t)c * mrows * 512, 2048, 16384, 512,
        (long long)mrows * 2048, (long long)2048, (long long)2048 * 512,
        2048, 1.0f, 8, mt, 4, linv + (size_t)c * mrows);
  }
}

// Round 11
// 155.390 us; speedup vs baseline: 1.0462x; 1.0462x over previous
//
#include <hip/hip_runtime.h>
#include <hip/hip_bf16.h>
#include <stdint.h>

typedef unsigned short u16;
typedef unsigned int u32;
typedef __bf16 bf16x8 __attribute__((ext_vector_type(8)));
typedef _Float16 f16x8 __attribute__((ext_vector_type(8)));
typedef float f32x4 __attribute__((ext_vector_type(4)));

#define LOG2E 1.4426950408889634f
#define QKSCALE 0.044194173824159216f  // 1/sqrt(512)

__device__ __forceinline__ u16 f2bf(float f) {
  u32 u = __builtin_bit_cast(u32, f);
  u += 0x7FFFu + ((u >> 16) & 1u);
  return (u16)(u >> 16);
}

__device__ __forceinline__ void gload_lds16(const void* g, void* l) {
  __builtin_amdgcn_global_load_lds(
      (const __attribute__((address_space(1))) u32*)g,
      (__attribute__((address_space(3))) u32*)l, 16, 0, 0);
}

// ---------------- concat + f32->bf16 ----------------
__global__ void k_concat_bf16(const float* __restrict__ x, const float* __restrict__ y,
                              u16* __restrict__ xyb) {
  int tid = blockIdx.x * blockDim.x + threadIdx.x;
  int e = tid * 4;
  int s = e >> 9;
  int d = e & 511;
  int b = s >> 11, r = s & 2047;
  const float* src = (r < 1024) ? (x + ((size_t)(b * 1024 + r) * 512 + d))
                                : (y + ((size_t)(b * 1024 + (r - 1024)) * 512 + d));
  float4 v = *(const float4*)src;
  ushort4 o;
  o.x = f2bf(v.x); o.y = f2bf(v.y); o.z = f2bf(v.z); o.w = f2bf(v.w);
  *(ushort4*)(xyb + e) = o;
}

// ---------------- W~ = Wq^T * Wk, e-split f32 partials ----------------
// grid 256 = 64 (i,j)-tiles x 4 e-groups(128 e); wpart[eg][j][i] (transposed: W~^T)
__global__ __launch_bounds__(256) void k_wtilde_part(const float* __restrict__ Wq,
                                                     const float* __restrict__ Wk,
                                                     float* __restrict__ wpart) {
  int blk = blockIdx.x;
  int eg = blk >> 6, tile = blk & 63;
  int i0 = (tile >> 3) * 64, j0 = (tile & 7) * 64;
  int t = threadIdx.x;
  __shared__ float qs[64][64], ks[64][64];
  int ti = t >> 4, tj = t & 15;
  float acc[4][4] = {};
  for (int ec = eg * 128; ec < eg * 128 + 128; ec += 64) {
    __syncthreads();
#pragma unroll
    for (int r = 0; r < 4; ++r) {
      int e = (t >> 4) + r * 16;
      int c = (t & 15) * 4;
      *(float4*)&qs[e][c] = *(const float4*)(Wq + (size_t)(ec + e) * 512 + i0 + c);
      *(float4*)&ks[e][c] = *(const float4*)(Wk + (size_t)(ec + e) * 512 + j0 + c);
    }
    __syncthreads();
#pragma unroll 8
    for (int e = 0; e < 64; ++e) {
      float4 qa = *(const float4*)&qs[e][ti * 4];
      float4 kb = *(const float4*)&ks[e][tj * 4];
      float qv[4] = {qa.x, qa.y, qa.z, qa.w}, kv[4] = {kb.x, kb.y, kb.z, kb.w};
#pragma unroll
      for (int a = 0; a < 4; ++a)
#pragma unroll
        for (int b = 0; b < 4; ++b) acc[a][b] += qv[a] * kv[b];
    }
  }
  float* base = wpart + (size_t)eg * 262144;
#pragma unroll
  for (int b = 0; b < 4; ++b) {
    float4 o = {acc[0][b], acc[1][b], acc[2][b], acc[3][b]};
    *(float4*)(base + (size_t)(j0 + tj * 4 + b) * 512 + i0 + ti * 4) = o;
  }
}

// ---------------- finalize W~T (sum partials, fold 1/sqrt(D), -> bf16) + Wv -> bf16 ----
__global__ __launch_bounds__(256) void k_wfin(const float* __restrict__ wpart,
                                              const float* __restrict__ Wv,
                                              u16* __restrict__ WtT, u16* __restrict__ Wvb) {
  int blk = blockIdx.x, t = threadIdx.x;
  if (blk < 64) {
    int base = blk * 4096 + t * 16;
#pragma unroll
    for (int g = 0; g < 4; ++g) {
      float4 s = *(const float4*)(wpart + base + g * 4);
#pragma unroll
      for (int eg = 1; eg < 4; ++eg) {
        float4 p = *(const float4*)(wpart + (size_t)eg * 262144 + base + g * 4);
        s.x += p.x; s.y += p.y; s.z += p.z; s.w += p.w;
      }
      ushort4 o;
      o.x = f2bf(s.x * QKSCALE); o.y = f2bf(s.y * QKSCALE);
      o.z = f2bf(s.z * QKSCALE); o.w = f2bf(s.w * QKSCALE);
      *(ushort4*)(WtT + base + g * 4) = o;
    }
  } else {
    int base = (blk - 64) * 65536;
#pragma unroll 16
    for (int r = 0; r < 64; ++r) {
      int e = base + (r * 256 + t) * 4;
      float4 v = *(const float4*)(Wv + e);
      ushort4 o;
      o.x = f2bf(v.x); o.y = f2bf(v.y); o.z = f2bf(v.z); o.w = f2bf(v.w);
      *(ushort4*)(Wvb + e) = o;
    }
  }
}

// ---------------- 256-tile GEMM (r4 schedule): C = scale * A * B^T ----------------
// BM=256, BK=64, 8 waves. BN=256: waves 2x4 (wave tile 128x64). BN=128: 4x2 (64x64).
// LDS rows 128B XOR-swizzled (pre-swizzled global_load_lds source), double-buffered;
// stage ALL of tile kt+1 at top of tile kt; one vmcnt(0)+barrier per tile.
// EXPSUM: C = exp2(acc*scale) f16 + row partial sums -> lextra[(z*2048+row)*ntiles+ty].
// DIVL:   C = acc*scale*lextra[z*2048+row] (f32 out), lextra = 1/l.
template <int BN, int ABF16, int OUTM, int EXPSUM, int DIVL>
__global__ __launch_bounds__(512, 2) void k_gemm256(
    const u16* __restrict__ A, const u16* __restrict__ B, void* __restrict__ Cv,
    int lda, int ldb, int ldc,
    long long sA, long long sB, long long sC,
    int K, float scale, int batches, int mtiles, int ntiles,
    float* __restrict__ lextra) {
  constexpr int M_rep = (BN == 256) ? 8 : 4;
  constexpr int WN = (BN == 256) ? 4 : 2;
  constexpr int NPH = (BN == 256) ? 4 : 2;
  constexpr int A_BYTES = 256 * 128;
  constexpr int B_BYTES = BN * 128;
  constexpr int BUFB = A_BYTES + B_BYTES;
  constexpr int RND_A = A_BYTES / 8192;  // 4
  constexpr int RND_B = B_BYTES / 8192;  // 4 / 2
  constexpr int RNDS = RND_A + RND_B;    // 8 / 6

  __shared__ __align__(16) char lds[2 * BUFB];

  int t = threadIdx.x;
  int lane = t & 63;
  int w = t >> 6;
  int wr = w / WN, wc = w % WN;

  int bid = blockIdx.x;
  long long z = bid % batches;
  int t2 = bid / batches;
  int tx = t2 % mtiles, ty = t2 / mtiles;

  size_t rsA = (size_t)lda * 2, rsB = (size_t)ldb * 2;
  int srow = t >> 3;
  int scb = ((t & 7) * 16) ^ ((srow & 7) << 4);  // pre-swizzled source byte col

  const char* Ab = (const char*)(A + z * sA + (size_t)tx * 256 * lda);
  const char* Bb = (const char*)(B + z * sB + (size_t)ty * BN * ldb);

  const char* gsrc[RNDS];
#pragma unroll
  for (int r = 0; r < RNDS; ++r) {
    if (r < RND_A) gsrc[r] = Ab + (size_t)(r * 64 + srow) * rsA + scb;
    else           gsrc[r] = Bb + (size_t)((r - RND_A) * 64 + srow) * rsB + scb;
  }

  auto stageAll = [&](int buf) {
#pragma unroll
    for (int r = 0; r < RNDS; ++r) {
      int off = ((r < RND_A) ? r * 8192 : A_BYTES + (r - RND_A) * 8192) + t * 16;
      gload_lds16(gsrc[r], lds + buf * BUFB + off);
      gsrc[r] += 128;  // advance one K-tile
    }
  };

  int axor = (lane & 7) << 4;
  int arow0 = wr * (M_rep * 16) + (lane & 15);
  int brow0 = wc * 64 + (lane & 15);
  int kb0 = (lane >> 4) * 16;

  f32x4 acc[M_rep][4] = {};
  int NT = K >> 6;

  stageAll(0);
  asm volatile("s_waitcnt vmcnt(0)" ::: "memory");
  __syncthreads();

  for (int kt = 0; kt < NT; ++kt) {
    const char* Abase = lds + (kt & 1) * BUFB;
    const char* Bbase = Abase + A_BYTES;
    if (kt + 1 < NT) stageAll((kt & 1) ^ 1);
    __builtin_amdgcn_sched_barrier(0);

    bf16x8 afr[4][2];
#pragma unroll
    for (int p = 0; p < NPH; ++p) {
      int mchunk = (p >> 1) * 4;
      int npair = (p & 1) * 2;
      if ((p & 1) == 0) {
#pragma unroll
        for (int i = 0; i < 4; ++i)
#pragma unroll
          for (int kk = 0; kk < 2; ++kk)
            afr[i][kk] = *(const bf16x8*)(Abase + (arow0 + (mchunk + i) * 16) * 128 +
                                          ((kb0 + kk * 64) ^ axor));
      }
      bf16x8 bfr[2][2];
#pragma unroll
      for (int j = 0; j < 2; ++j)
#pragma unroll
        for (int kk = 0; kk < 2; ++kk)
          bfr[j][kk] = *(const bf16x8*)(Bbase + (brow0 + (npair + j) * 16) * 128 +
                                        ((kb0 + kk * 64) ^ axor));
      __builtin_amdgcn_s_setprio(1);
#pragma unroll
      for (int i = 0; i < 4; ++i)
#pragma unroll
        for (int j = 0; j < 2; ++j)
#pragma unroll
          for (int kk = 0; kk < 2; ++kk) {
            if constexpr (ABF16) {
              acc[mchunk + i][npair + j] = __builtin_amdgcn_mfma_f32_16x16x32_f16(
                  __builtin_bit_cast(f16x8, afr[i][kk]), __builtin_bit_cast(f16x8, bfr[j][kk]),
                  acc[mchunk + i][npair + j], 0, 0, 0);
            } else {
              acc[mchunk + i][npair + j] = __builtin_amdgcn_mfma_f32_16x16x32_bf16(
                  afr[i][kk], bfr[j][kk], acc[mchunk + i][npair + j], 0, 0, 0);
            }
          }
      __builtin_amdgcn_s_setprio(0);
    }

    if (kt + 1 < NT) {
      asm volatile("s_waitcnt vmcnt(0)" ::: "memory");
      __syncthreads();
    }
  }

  // ---------------- epilogue ----------------
  float* lds_l = (float*)lds;  // [256][WN] row-sum staging (EXPSUM only)
  if constexpr (EXPSUM) __syncthreads();

#pragma unroll
  for (int m = 0; m < M_rep; ++m) {
    int lrow = wr * (M_rep * 16) + m * 16 + ((lane >> 4) << 2);
    int grow = tx * 256 + lrow;
#pragma unroll
    for (int r = 0; r < 4; ++r) {
      float rs = 0.0f;
      float linv_v = 1.0f;
      if constexpr (DIVL) linv_v = lextra[z * 2048 + grow + r];
#pragma unroll
      for (int n = 0; n < 4; ++n) {
        int col = ty * BN + wc * 64 + n * 16 + (lane & 15);
        float v = acc[m][n][r] * scale;
        size_t idx = (size_t)(z * sC) + (size_t)(grow + r) * ldc + col;
        if constexpr (EXPSUM) {
          _Float16 h = (_Float16)exp2f(v);
          ((_Float16*)Cv)[idx] = h;
          rs += (float)h;  // sum rounded values so O/l is unbiased
        } else if constexpr (OUTM == 0) {
          ((u16*)Cv)[idx] = f2bf(v);
        } else if constexpr (OUTM == 1) {
          ((_Float16*)Cv)[idx] = (_Float16)v;
        } else {
          ((float*)Cv)[idx] = v * linv_v;
        }
      }
      if constexpr (EXPSUM) {
        rs += __shfl_xor(rs, 1, 16);
        rs += __shfl_xor(rs, 2, 16);
        rs += __shfl_xor(rs, 4, 16);
        rs += __shfl_xor(rs, 8, 16);
        if ((lane & 15) == 0) lds_l[(lrow + r) * WN + wc] = rs;
      }
    }
  }

  if constexpr (EXPSUM) {
    __syncthreads();
    if (t < 256) {
      float s = 0.0f;
#pragma unroll
      for (int q = 0; q < WN; ++q) s += lds_l[t * WN + q];
      lextra[(z * 2048 + tx * 256 + t) * ntiles + ty] = s;
    }
  }
}

// ---------------- invert row sums ----------------
__global__ __launch_bounds__(256) void k_inv_l(const float* __restrict__ lpart,
                                               float* __restrict__ linv,
                                               int mrows, int rowoff, int nparts) {
  int tid = blockIdx.x * blockDim.x + threadIdx.x;
  int z = tid / mrows, lr = tid - z * mrows;
  int row = z * 2048 + rowoff + lr;
  const float* p = lpart + (size_t)row * nparts;
  float s = 0.0f;
  for (int q = 0; q < nparts; ++q) s += p[q];
  linv[row] = 1.0f / s;
}

extern "C" void kernel_launch(void* const* d_in, const int* in_sizes, int n_in,
                              void* d_out, int out_size, void* d_ws, size_t ws_size,
                              hipStream_t stream) {
  const float* x = (const float*)d_in[0];
  const float* y = (const float*)d_in[1];
  const float* Wq = (const float*)d_in[2];
  const float* Wk = (const float*)d_in[3];
  const float* Wv = (const float*)d_in[4];
  float* out = (float*)d_out;

  char* p = (char*)d_ws;
  u16* xyb = (u16*)p; p += (size_t)16384 * 512 * 2;   // concat bf16 (alive thru QK^T)
  u16* Qt  = (u16*)p; p += (size_t)16384 * 512 * 2;   // Q~ = xy*(W~/sqrtD) bf16
  u16* VTh = (u16*)p; p += (size_t)16384 * 512 * 2;   // V^T f16 [512][16384]
  float* lpart = (float*)p; p += (size_t)16384 * 8 * 4;
  float* linv = (float*)p; p += (size_t)16384 * 4;
  u16* WtT = (u16*)p; p += (size_t)512 * 512 * 2;     // W~^T bf16 (scale folded)
  u16* Wvb = (u16*)p; p += (size_t)512 * 512 * 2;
  size_t base = (size_t)(p - (char*)d_ws);
  float* wpart = (float*)p;    // 4 MB partials, dead before S written
  _Float16* Sb = (_Float16*)p; // S/P region

  int nc = (ws_size >= base + (size_t)16384 * 2048 * 2) ? 1 : 2;
  int mrows = 2048 / nc;
  int mt = mrows / 256;

  // converts + W~ precompute
  k_concat_bf16<<<8192, 256, 0, stream>>>(x, y, xyb);
  k_wtilde_part<<<256, 256, 0, stream>>>(Wq, Wk, wpart);
  k_wfin<<<68, 256, 0, stream>>>(wpart, Wv, WtT, Wvb);

  // Q~ projection: [16384][512] = xy @ WtT^T (bf16 out)
  k_gemm256<128, 0, 0, 0, 0><<<256, 512, 0, stream>>>(
      xyb, WtT, Qt, 512, 512, 512, 0, 0, 0, 512, 1.0f, 1, 64, 4, nullptr);
  // VT projection: [512][16384] = Wv @ xy^T (f16 out)
  k_gemm256<128, 0, 1, 0, 0><<<256, 512, 0, stream>>>(
      Wvb, xyb, VTh, 512, 512, 16384, 0, 0, 0, 512, 1.0f, 1, 2, 128, nullptr);

  for (int c = 0; c < nc; ++c) {
    const u16* Qc = Qt + (size_t)c * mrows * 512;
    // P = exp2(log2e * Q~ xy^T) (f16 out) + row partial sums -> lpart
    k_gemm256<256, 0, 1, 1, 0><<<8 * mt * 8, 512, 0, stream>>>(
        Qc, xyb, Sb, 512, 512, 2048,
        (long long)2048 * 512, (long long)2048 * 512, (long long)mrows * 2048,
        512, LOG2E, 8, mt, 8, lpart + (size_t)c * mrows * 8);
    // linv = 1 / rowsum
    k_inv_l<<<(8 * mrows) / 256, 256, 0, stream>>>(lpart, linv, mrows, c * mrows, 8);
    // O = (P @ VT^T) * linv (f16 in, f32 out)
    k_gemm256<128, 1, 2, 0, 1><<<8 * mt * 4, 512, 0, stream>>>(
        (const u16*)Sb, VTh, out + (size_t)c * mrows * 512, 2048, 16384, 512,
        (long long)mrows * 2048, (long long)2048, (long long)2048 * 512,
        2048, 1.0f, 8, mt, 4, linv + (size_t)c * mrows);
  }
}

// Round 12
// 141.263 us; speedup vs baseline: 1.1508x; 1.1000x over previous
//
#include <hip/hip_runtime.h>
#include <hip/hip_bf16.h>
#include <stdint.h>

typedef unsigned short u16;
typedef unsigned int u32;
typedef __bf16 bf16x8 __attribute__((ext_vector_type(8)));
typedef float f32x4 __attribute__((ext_vector_type(4)));

// 1/sqrt(512) * log2(e) — folded into Wq at convert time
#define WQ_SCALE (0.044194173824159216f * 1.4426950408889634f)

__device__ __forceinline__ u16 f2bf(float f) {
  u32 u = __builtin_bit_cast(u32, f);
  u += 0x7FFFu + ((u >> 16) & 1u);
  return (u16)(u >> 16);
}

__device__ __forceinline__ void gload_lds16(const void* g, void* l) {
  __builtin_amdgcn_global_load_lds(
      (const __attribute__((address_space(1))) u32*)g,
      (__attribute__((address_space(3))) u32*)l, 16, 0, 0);
}

// ---------------- concat + f32->bf16 ----------------
__global__ void k_concat_bf16(const float* __restrict__ x, const float* __restrict__ y,
                              u16* __restrict__ xyb) {
  int tid = blockIdx.x * blockDim.x + threadIdx.x;
  int e = tid * 4;
  int s = e >> 9;
  int d = e & 511;
  int b = s >> 11, r = s & 2047;
  const float* src = (r < 1024) ? (x + ((size_t)(b * 1024 + r) * 512 + d))
                                : (y + ((size_t)(b * 1024 + (r - 1024)) * 512 + d));
  float4 v = *(const float4*)src;
  ushort4 o;
  o.x = f2bf(v.x); o.y = f2bf(v.y); o.z = f2bf(v.z); o.w = f2bf(v.w);
  *(ushort4*)(xyb + e) = o;
}

// weights: Wq (scaled by WQ_SCALE), Wk -> Wqkb stacked; Wv -> Wvb
__global__ void k_w_to_bf16(const float* __restrict__ Wq, const float* __restrict__ Wk,
                            const float* __restrict__ Wv,
                            u16* __restrict__ Wqkb, u16* __restrict__ Wvb) {
  int tid = blockIdx.x * blockDim.x + threadIdx.x;  // 196608 threads
  int which = tid >> 16;
  int e = (tid & 65535) * 4;
  const float* src = (which == 0) ? Wq : (which == 1) ? Wk : Wv;
  u16* dst = (which == 0) ? Wqkb : (which == 1) ? (Wqkb + 262144) : Wvb;
  float sc = (which == 0) ? WQ_SCALE : 1.0f;
  float4 v = *(const float4*)(src + e);
  ushort4 o;
  o.x = f2bf(v.x * sc); o.y = f2bf(v.y * sc);
  o.z = f2bf(v.z * sc); o.w = f2bf(v.w * sc);
  *(ushort4*)(dst + e) = o;
}

// ---------------- 256-tile GEMM (r4 schedule): C = scale * A * B^T ----------------
// BM=256, BK=64, 8 waves, all-bf16 MFMA. BN=256: waves 2x4 (wave tile 128x64).
// BN=128: waves 4x2 (64x64). LDS rows 128B XOR-swizzled (pre-swizzled
// global_load_lds source), double-buffered; stage ALL of tile kt+1 at top of
// tile kt; one vmcnt(0)+barrier per tile.
// EXPSUM: C = bf16(exp2(acc)) + row partial sums -> lextra[(z*2048+row)*ntiles+ty]
//         (log2e/sqrtD pre-folded into A's weights upstream).
// DIVL:   C = f32(acc*scale*lextra[z*2048+row]), lextra = 1/l.
// Second operand set (A2..split): blocks with bid>=split compute an independent
// GEMM (used to merge the two projections into one full-occupancy launch).
template <int BN, int OUTM, int EXPSUM, int DIVL>
__global__ __launch_bounds__(512, 2) void k_gemm256(
    const u16* A_, const u16* B_, void* Cv_,
    int lda, int ldb, int ldc,
    long long sA, long long sB, long long sC,
    int K, float scale, int batches, int mtiles, int ntiles,
    float* __restrict__ lextra,
    const u16* A2, const u16* B2, void* Cv2,
    int lda2, int ldb2, int ldc2, int mtiles2, int ntiles2, int split) {
  constexpr int M_rep = (BN == 256) ? 8 : 4;
  constexpr int WN = (BN == 256) ? 4 : 2;
  constexpr int NPH = (BN == 256) ? 4 : 2;
  constexpr int A_BYTES = 256 * 128;
  constexpr int B_BYTES = BN * 128;
  constexpr int BUFB = A_BYTES + B_BYTES;
  constexpr int RND_A = A_BYTES / 8192;  // 4
  constexpr int RND_B = B_BYTES / 8192;  // 4 / 2
  constexpr int RNDS = RND_A + RND_B;    // 8 / 6

  __shared__ __align__(16) char lds[2 * BUFB];

  int t = threadIdx.x;
  int lane = t & 63;
  int w = t >> 6;
  int wr = w / WN, wc = w % WN;

  const u16* A = A_;
  const u16* B = B_;
  void* Cv = Cv_;
  int bid = blockIdx.x;
  if (split && bid >= split) {
    bid -= split;
    A = A2; B = B2; Cv = Cv2;
    lda = lda2; ldb = ldb2; ldc = ldc2;
    mtiles = mtiles2; ntiles = ntiles2;
  }

  long long z = bid % batches;
  int t2 = bid / batches;
  int tx = t2 % mtiles, ty = t2 / mtiles;

  size_t rsA = (size_t)lda * 2, rsB = (size_t)ldb * 2;
  int srow = t >> 3;
  int scb = ((t & 7) * 16) ^ ((srow & 7) << 4);  // pre-swizzled source byte col

  const char* Ab = (const char*)(A + z * sA + (size_t)tx * 256 * lda);
  const char* Bb = (const char*)(B + z * sB + (size_t)ty * BN * ldb);

  const char* gsrc[RNDS];
#pragma unroll
  for (int r = 0; r < RNDS; ++r) {
    if (r < RND_A) gsrc[r] = Ab + (size_t)(r * 64 + srow) * rsA + scb;
    else           gsrc[r] = Bb + (size_t)((r - RND_A) * 64 + srow) * rsB + scb;
  }

  auto stageAll = [&](int buf) {
#pragma unroll
    for (int r = 0; r < RNDS; ++r) {
      int off = ((r < RND_A) ? r * 8192 : A_BYTES + (r - RND_A) * 8192) + t * 16;
      gload_lds16(gsrc[r], lds + buf * BUFB + off);
      gsrc[r] += 128;  // advance one K-tile
    }
  };

  int axor = (lane & 7) << 4;
  int arow0 = wr * (M_rep * 16) + (lane & 15);
  int brow0 = wc * 64 + (lane & 15);
  int kb0 = (lane >> 4) * 16;

  f32x4 acc[M_rep][4] = {};
  int NT = K >> 6;

  stageAll(0);
  asm volatile("s_waitcnt vmcnt(0)" ::: "memory");
  __syncthreads();

  for (int kt = 0; kt < NT; ++kt) {
    const char* Abase = lds + (kt & 1) * BUFB;
    const char* Bbase = Abase + A_BYTES;
    if (kt + 1 < NT) stageAll((kt & 1) ^ 1);
    __builtin_amdgcn_sched_barrier(0);

    bf16x8 afr[4][2];
#pragma unroll
    for (int p = 0; p < NPH; ++p) {
      int mchunk = (p >> 1) * 4;
      int npair = (p & 1) * 2;
      if ((p & 1) == 0) {
#pragma unroll
        for (int i = 0; i < 4; ++i)
#pragma unroll
          for (int kk = 0; kk < 2; ++kk)
            afr[i][kk] = *(const bf16x8*)(Abase + (arow0 + (mchunk + i) * 16) * 128 +
                                          ((kb0 + kk * 64) ^ axor));
      }
      bf16x8 bfr[2][2];
#pragma unroll
      for (int j = 0; j < 2; ++j)
#pragma unroll
        for (int kk = 0; kk < 2; ++kk)
          bfr[j][kk] = *(const bf16x8*)(Bbase + (brow0 + (npair + j) * 16) * 128 +
                                        ((kb0 + kk * 64) ^ axor));
      __builtin_amdgcn_s_setprio(1);
#pragma unroll
      for (int i = 0; i < 4; ++i)
#pragma unroll
        for (int j = 0; j < 2; ++j)
#pragma unroll
          for (int kk = 0; kk < 2; ++kk)
            acc[mchunk + i][npair + j] = __builtin_amdgcn_mfma_f32_16x16x32_bf16(
                afr[i][kk], bfr[j][kk], acc[mchunk + i][npair + j], 0, 0, 0);
      __builtin_amdgcn_s_setprio(0);
    }

    if (kt + 1 < NT) {
      asm volatile("s_waitcnt vmcnt(0)" ::: "memory");
      __syncthreads();
    }
  }

  // ---------------- epilogue ----------------
  float* lds_l = (float*)lds;  // [256][WN] row-sum staging (EXPSUM only)
  if constexpr (EXPSUM) __syncthreads();

#pragma unroll
  for (int m = 0; m < M_rep; ++m) {
    int lrow = wr * (M_rep * 16) + m * 16 + ((lane >> 4) << 2);
    int grow = tx * 256 + lrow;
#pragma unroll
    for (int r = 0; r < 4; ++r) {
      float rs = 0.0f;
      float linv_v = 1.0f;
      if constexpr (DIVL) linv_v = lextra[z * 2048 + grow + r];
#pragma unroll
      for (int n = 0; n < 4; ++n) {
        int col = ty * BN + wc * 64 + n * 16 + (lane & 15);
        size_t idx = (size_t)(z * sC) + (size_t)(grow + r) * ldc + col;
        if constexpr (EXPSUM) {
          float e = exp2f(acc[m][n][r]);  // scale pre-folded into Wq
          ((u16*)Cv)[idx] = f2bf(e);
          rs += e;
        } else if constexpr (OUTM == 0) {
          ((u16*)Cv)[idx] = f2bf(acc[m][n][r] * scale);
        } else {
          ((float*)Cv)[idx] = acc[m][n][r] * scale * linv_v;
        }
      }
      if constexpr (EXPSUM) {
        rs += __shfl_xor(rs, 1, 16);
        rs += __shfl_xor(rs, 2, 16);
        rs += __shfl_xor(rs, 4, 16);
        rs += __shfl_xor(rs, 8, 16);
        if ((lane & 15) == 0) lds_l[(lrow + r) * WN + wc] = rs;
      }
    }
  }

  if constexpr (EXPSUM) {
    __syncthreads();
    if (t < 256) {
      float s = 0.0f;
#pragma unroll
      for (int q = 0; q < WN; ++q) s += lds_l[t * WN + q];
      lextra[(z * 2048 + tx * 256 + t) * ntiles + ty] = s;
    }
  }
}

// ---------------- invert row sums ----------------
__global__ __launch_bounds__(256) void k_inv_l(const float* __restrict__ lpart,
                                               float* __restrict__ linv,
                                               int mrows, int rowoff, int nparts) {
  int tid = blockIdx.x * blockDim.x + threadIdx.x;
  int z = tid / mrows, lr = tid - z * mrows;
  int row = z * 2048 + rowoff + lr;
  const float* p = lpart + (size_t)row * nparts;
  float s = 0.0f;
  for (int q = 0; q < nparts; ++q) s += p[q];
  linv[row] = 1.0f / s;
}

extern "C" void kernel_launch(void* const* d_in, const int* in_sizes, int n_in,
                              void* d_out, int out_size, void* d_ws, size_t ws_size,
                              hipStream_t stream) {
  const float* x = (const float*)d_in[0];
  const float* y = (const float*)d_in[1];
  const float* Wq = (const float*)d_in[2];
  const float* Wk = (const float*)d_in[3];
  const float* Wv = (const float*)d_in[4];
  float* out = (float*)d_out;

  char* p = (char*)d_ws;
  u16* QKb = (u16*)p; p += (size_t)16384 * 1024 * 2;  // Q cols 0-511 (pre-scaled), K cols 512-1023
  u16* VTb = (u16*)p; p += (size_t)16384 * 512 * 2;   // V^T bf16 [512][16384]
  float* lpart = (float*)p; p += (size_t)16384 * 8 * 4;
  float* linv = (float*)p; p += (size_t)16384 * 4;
  u16* Wqkb = (u16*)p; p += (size_t)1024 * 512 * 2;   // [scaled Wq; Wk]
  u16* Wvb = (u16*)p; p += (size_t)512 * 512 * 2;
  size_t base = (size_t)(p - (char*)d_ws);
  u16* xyb = (u16*)p;   // concat bf16; dead after merged projection
  u16* Sb = (u16*)p;    // P (bf16) aliases xyb

  int nc = (ws_size >= base + (size_t)16384 * 2048 * 2) ? 1 : 2;
  int mrows = 2048 / nc;
  int mt = mrows / 256;

  // converts
  k_concat_bf16<<<8192, 256, 0, stream>>>(x, y, xyb);
  k_w_to_bf16<<<768, 256, 0, stream>>>(Wq, Wk, Wv, Wqkb, Wvb);

  // merged projections, one full-occupancy launch (768 blocks):
  //   set1 (blocks 0-511):  QK = xy @ [cWq;Wk]^T  -> QKb [16384][1024] bf16
  //   set2 (blocks 512-767): VT = Wv @ xy^T       -> VTb [512][16384] bf16
  k_gemm256<128, 0, 0, 0><<<768, 512, 0, stream>>>(
      xyb, Wqkb, QKb, 512, 512, 1024, 0, 0, 0, 512, 1.0f, 1, 64, 8, nullptr,
      Wvb, xyb, VTb, 512, 512, 16384, 2, 128, 512);

  for (int c = 0; c < nc; ++c) {
    const u16* Qc = QKb + (size_t)c * mrows * 1024;
    // P = exp2(Q K^T) (bf16 out; log2e/sqrtD folded into Q) + row sums -> lpart
    k_gemm256<256, 0, 1, 0><<<8 * mt * 8, 512, 0, stream>>>(
        Qc, QKb + 512, Sb, 1024, 1024, 2048,
        (long long)2048 * 1024, (long long)2048 * 1024, (long long)mrows * 2048,
        512, 1.0f, 8, mt, 8, lpart + (size_t)c * mrows * 8,
        nullptr, nullptr, nullptr, 0, 0, 0, 0, 0, 0);
    // linv = 1 / rowsum
    k_inv_l<<<(8 * mrows) / 256, 256, 0, stream>>>(lpart, linv, mrows, c * mrows, 8);
    // O = (P @ VT^T) * linv (bf16 in, f32 out)
    k_gemm256<128, 2, 0, 1><<<8 * mt * 4, 512, 0, stream>>>(
        Sb, VTb, out + (size_t)c * mrows * 512, 2048, 16384, 512,
        (long long)mrows * 2048, (long long)2048, (long long)2048 * 512,
        2048, 1.0f, 8, mt, 4, linv + (size_t)c * mrows,
        nullptr, nullptr, nullptr, 0, 0, 0, 0, 0, 0);
  }
}

// Round 13
// 136.635 us; speedup vs baseline: 1.1898x; 1.0339x over previous
//
#include <hip/hip_runtime.h>
#include <hip/hip_bf16.h>
#include <stdint.h>

typedef unsigned short u16;
typedef unsigned int u32;
typedef __bf16 bf16x8 __attribute__((ext_vector_type(8)));
typedef float f32x4 __attribute__((ext_vector_type(4)));

// 1/sqrt(512) * log2(e) — folded into Wq at convert time
#define WQ_SCALE (0.044194173824159216f * 1.4426950408889634f)

__device__ __forceinline__ u16 f2bf(float f) {
  u32 u = __builtin_bit_cast(u32, f);
  u += 0x7FFFu + ((u >> 16) & 1u);
  return (u16)(u >> 16);
}

__device__ __forceinline__ void gload_lds16(const void* g, void* l) {
  __builtin_amdgcn_global_load_lds(
      (const __attribute__((address_space(1))) u32*)g,
      (__attribute__((address_space(3))) u32*)l, 16, 0, 0);
}

// ---------------- concat + f32->bf16 ----------------
__global__ void k_concat_bf16(const float* __restrict__ x, const float* __restrict__ y,
                              u16* __restrict__ xyb) {
  int tid = blockIdx.x * blockDim.x + threadIdx.x;
  int e = tid * 4;
  int s = e >> 9;
  int d = e & 511;
  int b = s >> 11, r = s & 2047;
  const float* src = (r < 1024) ? (x + ((size_t)(b * 1024 + r) * 512 + d))
                                : (y + ((size_t)(b * 1024 + (r - 1024)) * 512 + d));
  float4 v = *(const float4*)src;
  ushort4 o;
  o.x = f2bf(v.x); o.y = f2bf(v.y); o.z = f2bf(v.z); o.w = f2bf(v.w);
  *(ushort4*)(xyb + e) = o;
}

// weights: Wq (scaled by WQ_SCALE), Wk -> Wqkb stacked; Wv -> Wvb
__global__ void k_w_to_bf16(const float* __restrict__ Wq, const float* __restrict__ Wk,
                            const float* __restrict__ Wv,
                            u16* __restrict__ Wqkb, u16* __restrict__ Wvb) {
  int tid = blockIdx.x * blockDim.x + threadIdx.x;  // 196608 threads
  int which = tid >> 16;
  int e = (tid & 65535) * 4;
  const float* src = (which == 0) ? Wq : (which == 1) ? Wk : Wv;
  u16* dst = (which == 0) ? Wqkb : (which == 1) ? (Wqkb + 262144) : Wvb;
  float sc = (which == 0) ? WQ_SCALE : 1.0f;
  float4 v = *(const float4*)(src + e);
  ushort4 o;
  o.x = f2bf(v.x * sc); o.y = f2bf(v.y * sc);
  o.z = f2bf(v.z * sc); o.w = f2bf(v.w * sc);
  *(ushort4*)(dst + e) = o;
}

// ---------------- 256-tile GEMM (r4 schedule): C = scale * A * B^T ----------------
// BM=256, BK=64, 8 waves, all-bf16 MFMA. BN=256: waves 2x4 (wave tile 128x64).
// BN=128: waves 4x2 (64x64). LDS rows 128B XOR-swizzled (pre-swizzled
// global_load_lds source), double-buffered; stage ALL of tile kt+1 at top of
// tile kt; one vmcnt(0)+barrier per tile.
// EXPONLY: C = bf16(exp2(acc))  (log2e/sqrtD pre-folded into A's weights).
// PVL: accumulate l[m] = rowsum(A) via ones-operand MFMA alongside the main
//      MFMAs; C = f32(acc / l) — softmax normalization fully in-kernel.
// Second operand set (A2..split): blocks with bid>=split compute an independent
// GEMM (used to merge the two projections into one full-occupancy launch).
template <int BN, int OUTM, int EXPONLY, int PVL>
__global__ __launch_bounds__(512, 2) void k_gemm256(
    const u16* A_, const u16* B_, void* Cv_,
    int lda, int ldb, int ldc,
    long long sA, long long sB, long long sC,
    int K, float scale, int batches, int mtiles, int ntiles,
    const u16* A2, const u16* B2, void* Cv2,
    int lda2, int ldb2, int ldc2, int mtiles2, int ntiles2, int split) {
  constexpr int M_rep = (BN == 256) ? 8 : 4;
  constexpr int WN = (BN == 256) ? 4 : 2;
  constexpr int NPH = (BN == 256) ? 4 : 2;
  constexpr int A_BYTES = 256 * 128;
  constexpr int B_BYTES = BN * 128;
  constexpr int BUFB = A_BYTES + B_BYTES;
  constexpr int RND_A = A_BYTES / 8192;  // 4
  constexpr int RND_B = B_BYTES / 8192;  // 4 / 2
  constexpr int RNDS = RND_A + RND_B;    // 8 / 6

  __shared__ __align__(16) char lds[2 * BUFB];

  int t = threadIdx.x;
  int lane = t & 63;
  int w = t >> 6;
  int wr = w / WN, wc = w % WN;

  const u16* A = A_;
  const u16* B = B_;
  void* Cv = Cv_;
  int bid = blockIdx.x;
  if (split && bid >= split) {
    bid -= split;
    A = A2; B = B2; Cv = Cv2;
    lda = lda2; ldb = ldb2; ldc = ldc2;
    mtiles = mtiles2; ntiles = ntiles2;
  }

  long long z = bid % batches;
  int t2 = bid / batches;
  int tx = t2 % mtiles, ty = t2 / mtiles;

  size_t rsA = (size_t)lda * 2, rsB = (size_t)ldb * 2;
  int srow = t >> 3;
  int scb = ((t & 7) * 16) ^ ((srow & 7) << 4);  // pre-swizzled source byte col

  const char* Ab = (const char*)(A + z * sA + (size_t)tx * 256 * lda);
  const char* Bb = (const char*)(B + z * sB + (size_t)ty * BN * ldb);

  const char* gsrc[RNDS];
#pragma unroll
  for (int r = 0; r < RNDS; ++r) {
    if (r < RND_A) gsrc[r] = Ab + (size_t)(r * 64 + srow) * rsA + scb;
    else           gsrc[r] = Bb + (size_t)((r - RND_A) * 64 + srow) * rsB + scb;
  }

  auto stageAll = [&](int buf) {
#pragma unroll
    for (int r = 0; r < RNDS; ++r) {
      int off = ((r < RND_A) ? r * 8192 : A_BYTES + (r - RND_A) * 8192) + t * 16;
      gload_lds16(gsrc[r], lds + buf * BUFB + off);
      gsrc[r] += 128;  // advance one K-tile
    }
  };

  int axor = (lane & 7) << 4;
  int arow0 = wr * (M_rep * 16) + (lane & 15);
  int brow0 = wc * 64 + (lane & 15);
  int kb0 = (lane >> 4) * 16;

  f32x4 acc[M_rep][4] = {};
  f32x4 acc_l[M_rep] = {};  // PVL: rowsum accumulator (same fragment layout)
  bf16x8 ones;
#pragma unroll
  for (int j = 0; j < 8; ++j) ones[j] = (__bf16)1.0f;

  int NT = K >> 6;

  stageAll(0);
  asm volatile("s_waitcnt vmcnt(0)" ::: "memory");
  __syncthreads();

  for (int kt = 0; kt < NT; ++kt) {
    const char* Abase = lds + (kt & 1) * BUFB;
    const char* Bbase = Abase + A_BYTES;
    if (kt + 1 < NT) stageAll((kt & 1) ^ 1);
    __builtin_amdgcn_sched_barrier(0);

    bf16x8 afr[4][2];
#pragma unroll
    for (int p = 0; p < NPH; ++p) {
      int mchunk = (p >> 1) * 4;
      int npair = (p & 1) * 2;
      if ((p & 1) == 0) {
#pragma unroll
        for (int i = 0; i < 4; ++i)
#pragma unroll
          for (int kk = 0; kk < 2; ++kk)
            afr[i][kk] = *(const bf16x8*)(Abase + (arow0 + (mchunk + i) * 16) * 128 +
                                          ((kb0 + kk * 64) ^ axor));
      }
      bf16x8 bfr[2][2];
#pragma unroll
      for (int j = 0; j < 2; ++j)
#pragma unroll
        for (int kk = 0; kk < 2; ++kk)
          bfr[j][kk] = *(const bf16x8*)(Bbase + (brow0 + (npair + j) * 16) * 128 +
                                        ((kb0 + kk * 64) ^ axor));
      __builtin_amdgcn_s_setprio(1);
#pragma unroll
      for (int i = 0; i < 4; ++i)
#pragma unroll
        for (int j = 0; j < 2; ++j)
#pragma unroll
          for (int kk = 0; kk < 2; ++kk)
            acc[mchunk + i][npair + j] = __builtin_amdgcn_mfma_f32_16x16x32_bf16(
                afr[i][kk], bfr[j][kk], acc[mchunk + i][npair + j], 0, 0, 0);
      if constexpr (PVL) {
        if ((p & 1) == 0) {  // once per fresh A-chunk: l += A . ones
#pragma unroll
          for (int i = 0; i < 4; ++i)
#pragma unroll
            for (int kk = 0; kk < 2; ++kk)
              acc_l[mchunk + i] = __builtin_amdgcn_mfma_f32_16x16x32_bf16(
                  afr[i][kk], ones, acc_l[mchunk + i], 0, 0, 0);
        }
      }
      __builtin_amdgcn_s_setprio(0);
    }

    if (kt + 1 < NT) {
      asm volatile("s_waitcnt vmcnt(0)" ::: "memory");
      __syncthreads();
    }
  }

  // ---------------- epilogue ----------------
#pragma unroll
  for (int m = 0; m < M_rep; ++m) {
    int lrow = wr * (M_rep * 16) + m * 16 + ((lane >> 4) << 2);
    int grow = tx * 256 + lrow;
#pragma unroll
    for (int r = 0; r < 4; ++r) {
      float linv_v = 1.0f;
      if constexpr (PVL) linv_v = 1.0f / acc_l[m][r];
#pragma unroll
      for (int n = 0; n < 4; ++n) {
        int col = ty * BN + wc * 64 + n * 16 + (lane & 15);
        size_t idx = (size_t)(z * sC) + (size_t)(grow + r) * ldc + col;
        if constexpr (EXPONLY) {
          ((u16*)Cv)[idx] = f2bf(exp2f(acc[m][n][r]));  // scale pre-folded into Wq
        } else if constexpr (OUTM == 0) {
          ((u16*)Cv)[idx] = f2bf(acc[m][n][r] * scale);
        } else {
          ((float*)Cv)[idx] = acc[m][n][r] * linv_v;  // softmax-normalized PV
        }
      }
    }
  }
}

extern "C" void kernel_launch(void* const* d_in, const int* in_sizes, int n_in,
                              void* d_out, int out_size, void* d_ws, size_t ws_size,
                              hipStream_t stream) {
  const float* x = (const float*)d_in[0];
  const float* y = (const float*)d_in[1];
  const float* Wq = (const float*)d_in[2];
  const float* Wk = (const float*)d_in[3];
  const float* Wv = (const float*)d_in[4];
  float* out = (float*)d_out;

  char* p = (char*)d_ws;
  u16* QKb = (u16*)p; p += (size_t)16384 * 1024 * 2;  // Q cols 0-511 (pre-scaled), K cols 512-1023
  u16* VTb = (u16*)p; p += (size_t)16384 * 512 * 2;   // V^T bf16 [512][16384]
  u16* Wqkb = (u16*)p; p += (size_t)1024 * 512 * 2;   // [scaled Wq; Wk]
  u16* Wvb = (u16*)p; p += (size_t)512 * 512 * 2;
  size_t base = (size_t)(p - (char*)d_ws);
  u16* xyb = (u16*)p;   // concat bf16; dead after merged projection
  u16* Sb = (u16*)p;    // P (bf16) aliases xyb

  int nc = (ws_size >= base + (size_t)16384 * 2048 * 2) ? 1 : 2;
  int mrows = 2048 / nc;
  int mt = mrows / 256;

  // converts
  k_concat_bf16<<<8192, 256, 0, stream>>>(x, y, xyb);
  k_w_to_bf16<<<768, 256, 0, stream>>>(Wq, Wk, Wv, Wqkb, Wvb);

  // merged projections, one full-occupancy launch (768 blocks):
  //   set1 (blocks 0-511):  QK = xy @ [cWq;Wk]^T  -> QKb [16384][1024] bf16
  //   set2 (blocks 512-767): VT = Wv @ xy^T       -> VTb [512][16384] bf16
  k_gemm256<128, 0, 0, 0><<<768, 512, 0, stream>>>(
      xyb, Wqkb, QKb, 512, 512, 1024, 0, 0, 0, 512, 1.0f, 1, 64, 8,
      Wvb, xyb, VTb, 512, 512, 16384, 2, 128, 512);

  for (int c = 0; c < nc; ++c) {
    const u16* Qc = QKb + (size_t)c * mrows * 1024;
    // P = exp2(Q K^T) (bf16 out; log2e/sqrtD folded into Q)
    k_gemm256<256, 0, 1, 0><<<8 * mt * 8, 512, 0, stream>>>(
        Qc, QKb + 512, Sb, 1024, 1024, 2048,
        (long long)2048 * 1024, (long long)2048 * 1024, (long long)mrows * 2048,
        512, 1.0f, 8, mt, 8,
        nullptr, nullptr, nullptr, 0, 0, 0, 0, 0, 0);
    // O = (P @ VT^T) / rowsum(P)  (l computed in-kernel via ones-MFMA)
    k_gemm256<128, 2, 0, 1><<<8 * mt * 4, 512, 0, stream>>>(
        Sb, VTb, out + (size_t)c * mrows * 512, 2048, 16384, 512,
        (long long)mrows * 2048, (long long)2048, (long long)2048 * 512,
        2048, 1.0f, 8, mt, 4,
        nullptr, nullptr, nullptr, 0, 0, 0, 0, 0, 0);
  }
}